// Round 6
// baseline (1445.389 us; speedup 1.0000x reference)
//
#include <hip/hip_runtime.h>
#include <math.h>

// N=511 complete binary tree: nodes 0..254 internal (both children valid),
// 255..510 leaves. B=128, M=256, IN=512, R=64.
//
// Round-6 structure: LDS-free register GEMMs. The mfma_16x16x32_bf16 A/B
// fragment is 16 contiguous bytes per lane (lane&15 = row/col, lane>>4 =
// k-chunk), so fragments are loaded DIRECTLY from global memory:
//  - B (gate-interleaved weights, <=1.5 MB) stays L1/L2-resident across the
//    whole grid; A streams once per col-group (L2/L3 absorbs re-reads).
//  - Zero __syncthreads in the K-loop -> no vmcnt(0) barrier drains (round-5
//    rocprof: staged LDS structure was latency-bound, MfmaUtil 9%).
//  - K compile-time, fully unrolled; A-frags 1-deep ping-pong prefetch.
// Gate-interleaved weight columns (16 m-cols x all gates per wave tile) keep
// every LSTM-cell epilogue fused into its producing GEMM.
#define NNODE 511

typedef short s16x8 __attribute__((ext_vector_type(8)));
typedef float f32x4 __attribute__((ext_vector_type(4)));

#define MFMA(a, b, c) __builtin_amdgcn_mfma_f32_16x16x32_bf16(a, b, c, 0, 0, 0)

__device__ __forceinline__ unsigned short f2bf(float f) {
  unsigned int u = __builtin_bit_cast(unsigned int, f);
  u += 0x7fffu + ((u >> 16) & 1u);           // RNE
  return (unsigned short)(u >> 16);
}
__device__ __forceinline__ float sigf(float x) { return 1.0f / (1.0f + expf(-x)); }

// ---------------------------------------------------------------------------
// wte (B,511,512) fp32 -> xbf (node,b,k) bf16, node-major. One-time.
__global__ void k_prep_x(const float* __restrict__ w, unsigned short* __restrict__ xbf) {
  int o = (blockIdx.x * 256 + threadIdx.x) * 4;   // out elem: node*65536 + b*512 + k
  int node = o >> 16;
  int b = (o >> 9) & 127;
  int k = o & 511;
  const float4 v = *(const float4*)(w + ((size_t)b * NNODE + node) * 512 + k);
  unsigned int p0 = (unsigned int)f2bf(v.x) | ((unsigned int)f2bf(v.y) << 16);
  unsigned int p1 = (unsigned int)f2bf(v.z) | ((unsigned int)f2bf(v.w) << 16);
  *(uint2*)(xbf + o) = make_uint2(p0, p1);
}

// ---------------------------------------------------------------------------
// Gate-interleaved transposed weights (c = column index, k = reduction index):
//  WL2t (768,512):  c = 48G+16g+mi, g in {i,u,o}
//  WA2t (1280,320): c = 80G+16g+mi, g in {i,f,g,o,fh}
//  WH2t (1024,256): c = 64G+16g+mi, g in {i,f,g,o}
//  WEX2t(1024,768): c = 64G+16g+mi, g in {i,u,o,f}; k<256 h-weights, else x-weights
__global__ void k_prep_w(const float* __restrict__ Wix, const float* __restrict__ Wux,
                         const float* __restrict__ Wox, const float* __restrict__ Wfx,
                         const float* __restrict__ Wih, const float* __restrict__ Wuh,
                         const float* __restrict__ Woh, const float* __restrict__ Wfh,
                         const float* __restrict__ Wsi, const float* __restrict__ Wsh,
                         unsigned short* __restrict__ WL2t, unsigned short* __restrict__ WA2t,
                         unsigned short* __restrict__ WH2t, unsigned short* __restrict__ WEX2t) {
  int idx = blockIdx.x * 256 + threadIdx.x;
  if (idx < 393216) {                       // WL2t 768*512
    int c = idx >> 9, k = idx & 511;
    int G = c / 48, rem = c - G * 48, g = rem >> 4, mi = rem & 15, m = G * 16 + mi;
    const float* W = (g == 0) ? Wix : (g == 1) ? Wux : Wox;
    WL2t[idx] = f2bf(W[k * 256 + m]);
  } else if (idx < 802816) {                // WA2t 1280*320
    int o = idx - 393216;
    int c = o / 320, k = o - c * 320;
    int G = c / 80, rem = c - G * 80, g = rem >> 4, mi = rem & 15, m = G * 16 + mi;
    float v;
    if (g < 4) v = Wsi[k * 1024 + g * 256 + m];
    else       v = (k < 256) ? Wfh[k * 256 + m] : 0.0f;
    WA2t[o] = f2bf(v);
  } else if (idx < 1064960) {               // WH2t 1024*256
    int o = idx - 802816;
    int c = o >> 8, k = o & 255;
    int G = c >> 6, rem = c & 63, g = rem >> 4, mi = rem & 15, m = G * 16 + mi;
    WH2t[o] = f2bf(Wsh[k * 1024 + g * 256 + m]);
  } else if (idx < 1851392) {               // WEX2t 1024*768
    int o = idx - 1064960;
    int c = o / 768, k = o - c * 768;
    int G = c >> 6, rem = c & 63, g = rem >> 4, mi = rem & 15, m = G * 16 + mi;
    float v;
    if (k < 256) {
      v = (g == 0) ? Wih[k * 256 + m] : (g == 1) ? Wuh[k * 256 + m]
        : (g == 2) ? Woh[k * 256 + m] : 0.0f;
    } else {
      int k2 = k - 256;
      v = (g == 0) ? Wix[k2 * 256 + m] : (g == 1) ? Wux[k2 * 256 + m]
        : (g == 2) ? Wox[k2 * 256 + m] : Wfx[k2 * 256 + m];
    }
    WEX2t[o] = f2bf(v);
  }
}

// ---------------------------------------------------------------------------
// Leaf GEMM + epilogue. A = xbf leaf slice (32768 x 512 bf16), B = WL2t
// (K=512, gates i,u,o). Block = 4 waves x 64 rows = 256 rows x 48 cols.
__global__ __launch_bounds__(256) void k_leaf(
    const unsigned short* __restrict__ xleaf, const unsigned short* __restrict__ Bt,
    float* __restrict__ cbuf, unsigned short* __restrict__ Ain,
    const float* __restrict__ rel,
    const float* __restrict__ bix, const float* __restrict__ bih,
    const float* __restrict__ bux, const float* __restrict__ buh,
    const float* __restrict__ box, const float* __restrict__ boh) {
  const int t = threadIdx.x;
  const int wave = t >> 6, lane = t & 63;
  const int m16 = lane & 15, q = lane >> 4, q8 = q * 8;
  const int rowBase = blockIdx.y * 256;
  const int colBase = blockIdx.x * 48;
  const unsigned short* aP[4];
  const unsigned short* bP[3];
#pragma unroll
  for (int i = 0; i < 4; ++i)
    aP[i] = xleaf + (size_t)(rowBase + wave * 64 + i * 16 + m16) * 512 + q8;
#pragma unroll
  for (int j = 0; j < 3; ++j)
    bP[j] = Bt + (size_t)(colBase + j * 16 + m16) * 512 + q8;

  f32x4 acc[4][3] = {};
  s16x8 af[4], afn[4];
#pragma unroll
  for (int i = 0; i < 4; ++i) af[i] = *(const s16x8*)(aP[i]);
#pragma unroll
  for (int gk = 0; gk < 512; gk += 32) {
    if (gk + 32 < 512)
#pragma unroll
      for (int i = 0; i < 4; ++i) afn[i] = *(const s16x8*)(aP[i] + gk + 32);
    s16x8 bf[3];
#pragma unroll
    for (int j = 0; j < 3; ++j) bf[j] = *(const s16x8*)(bP[j] + gk);
#pragma unroll
    for (int i = 0; i < 4; ++i)
#pragma unroll
      for (int j = 0; j < 3; ++j) acc[i][j] = MFMA(af[i], bf[j], acc[i][j]);
#pragma unroll
    for (int i = 0; i < 4; ++i) af[i] = afn[i];
  }

  const int m = blockIdx.x * 16 + m16;
  float bi = bix[m] + bih[m];
  float bu = bux[m] + buh[m];
  float bo = box[m] + boh[m];
#pragma unroll
  for (int i = 0; i < 4; ++i)
#pragma unroll
    for (int r2 = 0; r2 < 4; ++r2) {
      int r = rowBase + wave * 64 + i * 16 + q * 4 + r2;
      int vg = r >> 7, b = r & 127;
      int node = 255 + vg;
      float ii = sigf(acc[i][0][r2] + bi);
      float uu = tanhf(acc[i][1][r2] + bu);
      float oo = sigf(acc[i][2][r2] + bo);
      float cc = ii * uu;
      float hh = oo * tanhf(cc);
      cbuf[((size_t)node * 128 + b) * 256 + m] = cc;
      int rowA = (vg & 1) * 16384 + (vg >> 1) * 128 + b;
      Ain[(size_t)rowA * 320 + m] = f2bf(hh);
      if (m < 64)
        Ain[(size_t)rowA * 320 + 256 + m] = f2bf(rel[((size_t)b * NNODE + node) * 64 + m]);
    }
}

// ---------------------------------------------------------------------------
// GEMM1 + cell1 epilogue. A = [AinL ; AinR] (2*crows x 320 bf16), B = WA2t
// (K=320, gates i,f,g,o,fh). L rows -> h1,c1,FHL; R rows -> PR, FHR.
__global__ __launch_bounds__(256) void k_gemm1(
    const unsigned short* __restrict__ AinL, const unsigned short* __restrict__ AinR,
    const unsigned short* __restrict__ Bt,
    unsigned short* __restrict__ h1, float* __restrict__ c1,
    float* __restrict__ FHL, float* __restrict__ FHR, float* __restrict__ PR,
    const float* __restrict__ bsi, const float* __restrict__ bsh, int crows) {
  const int t = threadIdx.x;
  const int wave = t >> 6, lane = t & 63;
  const int m16 = lane & 15, q = lane >> 4, q8 = q * 8;
  const int rowBase = blockIdx.y * 256;
  const int colBase = blockIdx.x * 80;
  const unsigned short* aP[4];
  const unsigned short* bP[5];
#pragma unroll
  for (int i = 0; i < 4; ++i) {
    int r = rowBase + wave * 64 + i * 16 + m16;
    aP[i] = (r < crows ? AinL + (size_t)r * 320 : AinR + (size_t)(r - crows) * 320) + q8;
  }
#pragma unroll
  for (int j = 0; j < 5; ++j)
    bP[j] = Bt + (size_t)(colBase + j * 16 + m16) * 320 + q8;

  f32x4 acc[4][5] = {};
  s16x8 af[4], afn[4];
#pragma unroll
  for (int i = 0; i < 4; ++i) af[i] = *(const s16x8*)(aP[i]);
#pragma unroll
  for (int gk = 0; gk < 320; gk += 32) {
    if (gk + 32 < 320)
#pragma unroll
      for (int i = 0; i < 4; ++i) afn[i] = *(const s16x8*)(aP[i] + gk + 32);
    s16x8 bf[5];
#pragma unroll
    for (int j = 0; j < 5; ++j) bf[j] = *(const s16x8*)(bP[j] + gk);
#pragma unroll
    for (int i = 0; i < 4; ++i)
#pragma unroll
      for (int j = 0; j < 5; ++j) acc[i][j] = MFMA(af[i], bf[j], acc[i][j]);
#pragma unroll
    for (int i = 0; i < 4; ++i) af[i] = afn[i];
  }

  const int m = blockIdx.x * 16 + m16;
  float bi = bsi[m] + bsh[m];
  float bg = bsi[512 + m] + bsh[512 + m];
  float bo = bsi[768 + m] + bsh[768 + m];
#pragma unroll
  for (int i = 0; i < 4; ++i)
#pragma unroll
    for (int r2 = 0; r2 < 4; ++r2) {
      int r = rowBase + wave * 64 + i * 16 + q * 4 + r2;
      if (r < crows) {
        float ii = sigf(acc[i][0][r2] + bi);
        float gg = tanhf(acc[i][2][r2] + bg);
        float oo = sigf(acc[i][3][r2] + bo);
        float cv = ii * gg;
        size_t o = (size_t)r * 256 + m;
        h1[o] = f2bf(oo * tanhf(cv));
        c1[o] = cv;
        FHL[o] = acc[i][4][r2];
      } else {
        size_t o = (size_t)(r - crows) * 256 + m;
        float4 pv = {acc[i][0][r2], acc[i][1][r2], acc[i][2][r2], acc[i][3][r2]};
        *(float4*)(PR + o * 4) = pv;
        FHR[o] = acc[i][4][r2];
      }
    }
}

// ---------------------------------------------------------------------------
// GEMM2 + cell2 epilogue. A = h1 (crows x 256), B = WH2t (K=256, i,f,g,o).
// g = acc + PR + b_seq; h_tilde -> HT (bf16).
__global__ __launch_bounds__(256) void k_gemm2(
    const unsigned short* __restrict__ A, const unsigned short* __restrict__ Bt,
    const float* __restrict__ PR, const float* __restrict__ c1,
    unsigned short* __restrict__ HT,
    const float* __restrict__ bsi, const float* __restrict__ bsh, int rows) {
  const int t = threadIdx.x;
  const int wave = t >> 6, lane = t & 63;
  const int m16 = lane & 15, q = lane >> 4, q8 = q * 8;
  const int rowBase = blockIdx.y * 256;
  const int colBase = blockIdx.x * 64;
  const unsigned short* aP[4];
  const unsigned short* bP[4];
#pragma unroll
  for (int i = 0; i < 4; ++i) {
    int r = rowBase + wave * 64 + i * 16 + m16;
    if (r >= rows) r = rows - 1;
    aP[i] = A + (size_t)r * 256 + q8;
  }
#pragma unroll
  for (int j = 0; j < 4; ++j)
    bP[j] = Bt + (size_t)(colBase + j * 16 + m16) * 256 + q8;

  f32x4 acc[4][4] = {};
  s16x8 af[4], afn[4];
#pragma unroll
  for (int i = 0; i < 4; ++i) af[i] = *(const s16x8*)(aP[i]);
#pragma unroll
  for (int gk = 0; gk < 256; gk += 32) {
    if (gk + 32 < 256)
#pragma unroll
      for (int i = 0; i < 4; ++i) afn[i] = *(const s16x8*)(aP[i] + gk + 32);
    s16x8 bf[4];
#pragma unroll
    for (int j = 0; j < 4; ++j) bf[j] = *(const s16x8*)(bP[j] + gk);
#pragma unroll
    for (int i = 0; i < 4; ++i)
#pragma unroll
      for (int j = 0; j < 4; ++j) acc[i][j] = MFMA(af[i], bf[j], acc[i][j]);
#pragma unroll
    for (int i = 0; i < 4; ++i) af[i] = afn[i];
  }

  const int m = blockIdx.x * 16 + m16;
  float b0 = bsi[m] + bsh[m];
  float b1 = bsi[256 + m] + bsh[256 + m];
  float b2 = bsi[512 + m] + bsh[512 + m];
  float b3 = bsi[768 + m] + bsh[768 + m];
#pragma unroll
  for (int i = 0; i < 4; ++i)
#pragma unroll
    for (int r2 = 0; r2 < 4; ++r2) {
      int r = rowBase + wave * 64 + i * 16 + q * 4 + r2;
      if (r >= rows) continue;
      size_t o = (size_t)r * 256 + m;
      float4 pv = *(const float4*)(PR + o * 4);
      float ii = sigf(acc[i][0][r2] + pv.x + b0);
      float ff = sigf(acc[i][1][r2] + pv.y + b1);
      float gg = tanhf(acc[i][2][r2] + pv.z + b2);
      float oo = sigf(acc[i][3][r2] + pv.w + b3);
      float c2 = ff * c1[o] + ii * gg;
      HT[o] = f2bf(oo * tanhf(c2));
    }
}

// ---------------------------------------------------------------------------
// GEMM3 + node-gate epilogue. A = [HT (k<256) | xnode (k>=256)] (crows x 768),
// B = WEX2t (K=768, gates i,u,o,f). Uses FHL/FHR + children cbuf.
// lvl>0: write cbuf + parent Ain. lvl==0: write d_out fp32.
__global__ __launch_bounds__(256) void k_gemm3(
    const unsigned short* __restrict__ HT, const unsigned short* __restrict__ xnode,
    const unsigned short* __restrict__ Bt,
    const float* __restrict__ FHL, const float* __restrict__ FHR,
    float* __restrict__ cbuf, unsigned short* __restrict__ Ain,
    const float* __restrict__ rel, float* __restrict__ out,
    const float* __restrict__ bix, const float* __restrict__ bih,
    const float* __restrict__ bux, const float* __restrict__ buh,
    const float* __restrict__ box, const float* __restrict__ boh,
    const float* __restrict__ bfx, const float* __restrict__ bfh,
    int base, int v0, int n, int lvl, int rows) {
  const int t = threadIdx.x;
  const int wave = t >> 6, lane = t & 63;
  const int m16 = lane & 15, q = lane >> 4, q8 = q * 8;
  const int rowBase = blockIdx.y * 256;
  const int colBase = blockIdx.x * 64;
  const unsigned short* aH[4];   // HT rows, k offset direct
  const unsigned short* aX[4];   // xnode rows, pre-shifted so +gk works for gk>=256
  const unsigned short* bP[4];
#pragma unroll
  for (int i = 0; i < 4; ++i) {
    int r = rowBase + wave * 64 + i * 16 + m16;
    if (r >= rows) r = rows - 1;
    aH[i] = HT + (size_t)r * 256 + q8;
    aX[i] = xnode + (size_t)r * 512 + q8 - 256;
  }
#pragma unroll
  for (int j = 0; j < 4; ++j)
    bP[j] = Bt + (size_t)(colBase + j * 16 + m16) * 768 + q8;

  f32x4 acc[4][4] = {};
  s16x8 af[4], afn[4];
#pragma unroll
  for (int i = 0; i < 4; ++i) af[i] = *(const s16x8*)(aH[i]);
#pragma unroll
  for (int gk = 0; gk < 768; gk += 32) {
    int gkn = gk + 32;
    if (gkn < 768) {
#pragma unroll
      for (int i = 0; i < 4; ++i)
        afn[i] = *(const s16x8*)((gkn < 256 ? aH[i] : aX[i]) + gkn);
    }
    s16x8 bf[4];
#pragma unroll
    for (int j = 0; j < 4; ++j) bf[j] = *(const s16x8*)(bP[j] + gk);
#pragma unroll
    for (int i = 0; i < 4; ++i)
#pragma unroll
      for (int j = 0; j < 4; ++j) acc[i][j] = MFMA(af[i], bf[j], acc[i][j]);
#pragma unroll
    for (int i = 0; i < 4; ++i) af[i] = afn[i];
  }

  const int m = blockIdx.x * 16 + m16;
  float bi = bix[m] + bih[m];
  float bu = bux[m] + buh[m];
  float bo = box[m] + boh[m];
  float bf_ = bfx[m] + bfh[m];
#pragma unroll
  for (int i = 0; i < 4; ++i)
#pragma unroll
    for (int r2 = 0; r2 < 4; ++r2) {
      int r = rowBase + wave * 64 + i * 16 + q * 4 + r2;
      if (r >= rows) continue;
      int vloc = r >> 7, b = r & 127;
      int vg = v0 + vloc;
      int node = base + vg;
      int ch0 = 2 * node + 1;
      size_t o = (size_t)r * 256 + m;
      float pf = acc[i][3][r2] + bf_;
      float f0 = sigf(pf + FHL[o]);
      float f1 = sigf(pf + FHR[o]);
      float ii = sigf(acc[i][0][r2] + bi);
      float uu = tanhf(acc[i][1][r2] + bu);
      float oo = sigf(acc[i][2][r2] + bo);
      float cc = ii * uu + f0 * cbuf[((size_t)ch0 * 128 + b) * 256 + m]
                         + f1 * cbuf[((size_t)(ch0 + 1) * 128 + b) * 256 + m];
      float hh = oo * tanhf(cc);
      if (lvl == 0) {
        out[b * 256 + m] = hh;
      } else {
        cbuf[((size_t)node * 128 + b) * 256 + m] = cc;
        int rowA = (vg & 1) * (n >> 1) * 128 + (vg >> 1) * 128 + b;
        Ain[(size_t)rowA * 320 + m] = f2bf(hh);
        if (m < 64)
          Ain[(size_t)rowA * 320 + 256 + m] = f2bf(rel[((size_t)b * NNODE + node) * 64 + m]);
      }
    }
}

// ---------------------------------------------------------------------------
extern "C" void kernel_launch(void* const* d_in, const int* in_sizes, int n_in,
                              void* d_out, int out_size, void* d_ws, size_t ws_size,
                              hipStream_t stream) {
  const float* wte = (const float*)d_in[0];
  const float* rel = (const float*)d_in[1];
  const float* Wix = (const float*)d_in[3];
  const float* bix = (const float*)d_in[4];
  const float* Wfx = (const float*)d_in[5];
  const float* bfx = (const float*)d_in[6];
  const float* Wux = (const float*)d_in[7];
  const float* bux = (const float*)d_in[8];
  const float* Wox = (const float*)d_in[9];
  const float* box = (const float*)d_in[10];
  const float* Wih = (const float*)d_in[11];
  const float* bih = (const float*)d_in[12];
  const float* Wfh = (const float*)d_in[13];
  const float* bfh = (const float*)d_in[14];
  const float* Wuh = (const float*)d_in[15];
  const float* buh = (const float*)d_in[16];
  const float* Woh = (const float*)d_in[17];
  const float* boh = (const float*)d_in[18];
  const float* Wsi = (const float*)d_in[19];
  const float* Wsh = (const float*)d_in[20];
  const float* bsi = (const float*)d_in[21];
  const float* bsh = (const float*)d_in[22];
  float* out = (float*)d_out;
  (void)in_sizes; (void)n_in; (void)out_size;

  int INT_MAXN;
  if (ws_size >= (size_t)310 * 1024 * 1024)      INT_MAXN = 128;
  else if (ws_size >= (size_t)200 * 1024 * 1024) INT_MAXN = 32;
  else                                           INT_MAXN = 8;
  const int crowsMax = INT_MAXN * 128;

  char* ws = (char*)d_ws;
  size_t off = 0;
  auto alloc = [&](size_t bytes) {
    size_t o = off; off += (bytes + 255) & ~(size_t)255; return o;
  };
  unsigned short* xbf  = (unsigned short*)(ws + alloc((size_t)NNODE * 128 * 512 * 2));
  float*          cbuf = (float*)         (ws + alloc((size_t)NNODE * 128 * 256 * 4));
  unsigned short* Ain  = (unsigned short*)(ws + alloc((size_t)32768 * 320 * 2));
  unsigned short* WL2t = (unsigned short*)(ws + alloc((size_t)768 * 512 * 2));
  unsigned short* WA2t = (unsigned short*)(ws + alloc((size_t)1280 * 320 * 2));
  unsigned short* WH2t = (unsigned short*)(ws + alloc((size_t)1024 * 256 * 2));
  unsigned short* WEX2t= (unsigned short*)(ws + alloc((size_t)1024 * 768 * 2));
  unsigned short* h1   = (unsigned short*)(ws + alloc((size_t)crowsMax * 256 * 2));
  float*          c1   = (float*)         (ws + alloc((size_t)crowsMax * 256 * 4));
  float*          FHL  = (float*)         (ws + alloc((size_t)crowsMax * 256 * 4));
  float*          FHR  = (float*)         (ws + alloc((size_t)crowsMax * 256 * 4));
  float*          PR   = (float*)         (ws + alloc((size_t)crowsMax * 1024 * 4));
  unsigned short* HT   = (unsigned short*)(ws + alloc((size_t)crowsMax * 256 * 2));

  k_prep_x<<<32704, 256, 0, stream>>>(wte, xbf);
  k_prep_w<<<7232, 256, 0, stream>>>(Wix, Wux, Wox, Wfx, Wih, Wuh, Woh, Wfh,
                                     Wsi, Wsh, WL2t, WA2t, WH2t, WEX2t);

  // Leaves: one fused GEMM over xbf rows [255*128, 511*128).
  k_leaf<<<dim3(16, 128), 256, 0, stream>>>(xbf + (size_t)255 * 128 * 512, WL2t,
                                            cbuf, Ain, rel, bix, bih, bux, buh, box, boh);

  // Internal levels 7..0, 3 fused launches per chunk.
  for (int lvl = 7; lvl >= 0; --lvl) {
    int n = 1 << lvl;
    int base = n - 1;
    int cn = (n < INT_MAXN) ? n : INT_MAXN;
    for (int v0 = 0; v0 < n; v0 += cn) {
      int crows = cn * 128;
      int yb = (crows + 255) >> 8;           // row-blocks of 256 for gemm2/3
      const unsigned short* AinL = Ain + (size_t)(v0 * 128) * 320;
      const unsigned short* AinR = Ain + (size_t)((n + v0) * 128) * 320;
      const unsigned short* xnode = xbf + (size_t)(base + v0) * 128 * 512;
      k_gemm1<<<dim3(16, (2 * crows) >> 8), 256, 0, stream>>>(
          AinL, AinR, WA2t, h1, c1, FHL, FHR, PR, bsi, bsh, crows);
      k_gemm2<<<dim3(16, yb), 256, 0, stream>>>(h1, WH2t, PR, c1, HT, bsi, bsh, crows);
      k_gemm3<<<dim3(16, yb), 256, 0, stream>>>(HT, xnode, WEX2t, FHL, FHR, cbuf, Ain,
                                                rel, out, bix, bih, bux, buh, box, boh,
                                                bfx, bfh, base, v0, n, lvl, crows);
    }
  }
}